// Round 6
// baseline (267.546 us; speedup 1.0000x reference)
//
#include <hip/hip_runtime.h>

typedef _Float16 half8  __attribute__((ext_vector_type(8)));
typedef _Float16 half4v __attribute__((ext_vector_type(4)));
typedef __fp16   pk2    __attribute__((ext_vector_type(2)));  // cvt_pkrtz result type
typedef float    f32x16 __attribute__((ext_vector_type(16)));

constexpr int CL = 2048, CH = 16, CE = 64;
constexpr int RS = CH * CE;  // 1024 floats between consecutive seq positions

union H8 { half8 v; pk2 h[4]; unsigned u[4]; };
union H4 { half4v v; pk2 h[2]; };
union H2 { pk2 h; unsigned u; };

// XOR swizzle on the inner (k/e) index, in units of 8 halves (16B).
__device__ __forceinline__ int swz(int r) { return ((r ^ (r >> 3)) & 7) << 3; }

__global__ __launch_bounds__(512, 4)
void attn512(const float* __restrict__ Q, const float* __restrict__ K,
             const float* __restrict__ V, float* __restrict__ O) {
  // element (row, e) of K tile at KS[row*64 + (e ^ swz(row))]
  // element (k, d) of V tile at VT[d*64 + (k ^ swz(d))]   (transposed)
  __shared__ _Float16 KS[2][64 * 64];
  __shared__ _Float16 VT[2][64 * 64];

  const int tid = threadIdx.x;
  const int w  = tid >> 6, l = tid & 63;   // 8 waves/block
  const int hi = l >> 5,  ql = l & 31;

  const int bid = blockIdx.x;
  const int bh  = bid & 63;                 // heads fastest; bh-sharers 64 apart -> same XCD
  const int qsl = bid >> 6;                 // 0..7
  // balanced pairing: early half heavy (qs 7..4), late half light (0..3); qs+qs'=7 per CU
  const int qs  = (qsl < 4) ? (7 - qsl) : (qsl - 4);
  const int b = bh >> 4, h = bh & 15;
  const int qg0 = qs * 256 + w * 32;        // wave's first q row
  const int qg  = qg0 + ql;                 // lane's q row

  // ---- Q^T B-frags (swapped QK^T): lane = col q, e-rows hi*8..+7 per 16-e chunk ----
  const float* qptr = Q + ((size_t)(b * CL + qg) * CH + h) * CE;
  const float qs_ = 0.125f * 1.44269504089f;  // softmax scale * log2(e)
  half8 qf[4];
#pragma unroll
  for (int c = 0; c < 4; ++c) {
    const float4 x0 = *(const float4*)(qptr + c * 16 + hi * 8);
    const float4 x1 = *(const float4*)(qptr + c * 16 + hi * 8 + 4);
    H8 t;
    t.h[0] = __builtin_amdgcn_cvt_pkrtz(x0.x * qs_, x0.y * qs_);
    t.h[1] = __builtin_amdgcn_cvt_pkrtz(x0.z * qs_, x0.w * qs_);
    t.h[2] = __builtin_amdgcn_cvt_pkrtz(x1.x * qs_, x1.y * qs_);
    t.h[3] = __builtin_amdgcn_cvt_pkrtz(x1.z * qs_, x1.w * qs_);
    qf[c] = t.v;
  }

  f32x16 acc0, acc1;  // O^T accumulators: col q=ql lane-local
#pragma unroll
  for (int i = 0; i < 16; ++i) { acc0[i] = 0.f; acc1[i] = 0.f; }
  float m_ = -1e30f, l_ = 0.f;

  const float* Kb = K + ((size_t)b * CL * CH + h) * CE;
  const float* Vb = V + ((size_t)b * CL * CH + h) * CE;

  const int r0 = tid >> 4;  // staging row-within-32 (0..31)
  const int c4 = tid & 15;  // staging 16B column

  const int ktmax  = 4 * qs + 3;         // block's last 64-key tile (odd -> even tile count)
  const int ktlast = 4 * qs + (w >> 1);  // wave's diagonal tile

  auto stage_write = [&](int buf, int i, const float4& kx, const float4& vx) {
    const int row = i * 32 + r0;         // key index within tile
    H4 t;
    t.h[0] = __builtin_amdgcn_cvt_pkrtz(kx.x, kx.y);
    t.h[1] = __builtin_amdgcn_cvt_pkrtz(kx.z, kx.w);
    *(half4v*)&KS[buf][row * 64 + ((c4 * 4) ^ swz(row))] = t.v;
    VT[buf][(c4 * 4 + 0) * 64 + (row ^ swz(c4 * 4 + 0))] = (_Float16)vx.x;
    VT[buf][(c4 * 4 + 1) * 64 + (row ^ swz(c4 * 4 + 1))] = (_Float16)vx.y;
    VT[buf][(c4 * 4 + 2) * 64 + (row ^ swz(c4 * 4 + 2))] = (_Float16)vx.z;
    VT[buf][(c4 * 4 + 3) * 64 + (row ^ swz(c4 * 4 + 3))] = (_Float16)vx.w;
  };

  // ---- prologue: stage tile 0 into buffer 0 ----
#pragma unroll
  for (int i = 0; i < 2; ++i) {
    const int row = i * 32 + r0;
    const float4 kx = *(const float4*)(Kb + (size_t)row * RS + c4 * 4);
    const float4 vx = *(const float4*)(Vb + (size_t)row * RS + c4 * 4);
    stage_write(0, i, kx, vx);
  }

  auto phase = [&](const int kt, const int cur) {
    __syncthreads();  // staged writes to cur visible; prior reads of cur^1 done

    // issue next-tile global loads early
    float4 kst[2], vst[2];
    const bool doStage = (kt < ktmax);
    if (doStage) {
      const int kb1 = (kt + 1) * 64;
#pragma unroll
      for (int i = 0; i < 2; ++i) {
        const int row = kb1 + i * 32 + r0;
        kst[i] = *(const float4*)(Kb + (size_t)row * RS + c4 * 4);
        vst[i] = *(const float4*)(Vb + (size_t)row * RS + c4 * 4);
      }
    }

    if (kt <= ktlast) {
      const int kb = kt * 64;
      const bool do1 = (qg0 + 31) >= (kb + 32);  // second 32-key half valid (wave-uniform)

      // ---- swapped QK^T: S^T[k][q] = K_tile · Q^T ----
      f32x16 st0, st1;
#pragma unroll
      for (int i = 0; i < 16; ++i) { st0[i] = 0.f; st1[i] = 0.f; }
      __builtin_amdgcn_s_setprio(1);
#pragma unroll
      for (int c = 0; c < 4; ++c) {
        const half8 ka = *(const half8*)&KS[cur][ql * 64 + ((c * 16 + hi * 8) ^ swz(ql))];
        st0 = __builtin_amdgcn_mfma_f32_32x32x16_f16(ka, qf[c], st0, 0, 0, 0);
      }
      if (do1) {
#pragma unroll
        for (int c = 0; c < 4; ++c) {
          const int row = 32 + ql;
          const half8 ka = *(const half8*)&KS[cur][row * 64 + ((c * 16 + hi * 8) ^ swz(row))];
          st1 = __builtin_amdgcn_mfma_f32_32x32x16_f16(ka, qf[c], st1, 0, 0, 0);
        }
      }
      __builtin_amdgcn_s_setprio(0);

      // ---- causal mask (diagonal tile only); reg r -> k row (r&3)+8*(r>>2)+4*hi ----
      if (kt == ktlast) {
#pragma unroll
        for (int r = 0; r < 16; ++r) {
          const int ko = (r & 3) + 8 * (r >> 2) + 4 * hi;
          if (kb + ko > qg) st0[r] = -1e30f;
          if (kb + 32 + ko > qg) st1[r] = -1e30f;
        }
      }

      // ---- in-lane online softmax with defer-max (T13) ----
      float mt;
      {
        float a = fmaxf(fmaxf(fmaxf(st0[0], st0[1]), fmaxf(st0[2], st0[3])),
                        fmaxf(fmaxf(st0[4], st0[5]), fmaxf(st0[6], st0[7])));
        float bm = fmaxf(fmaxf(fmaxf(st0[8], st0[9]), fmaxf(st0[10], st0[11])),
                         fmaxf(fmaxf(st0[12], st0[13]), fmaxf(st0[14], st0[15])));
        mt = fmaxf(a, bm);
        if (do1) {
          float c2 = fmaxf(fmaxf(fmaxf(st1[0], st1[1]), fmaxf(st1[2], st1[3])),
                           fmaxf(fmaxf(st1[4], st1[5]), fmaxf(st1[6], st1[7])));
          float d2 = fmaxf(fmaxf(fmaxf(st1[8], st1[9]), fmaxf(st1[10], st1[11])),
                           fmaxf(fmaxf(st1[12], st1[13]), fmaxf(st1[14], st1[15])));
          mt = fmaxf(mt, fmaxf(c2, d2));
        }
      }
      mt = fmaxf(mt, __shfl_xor(mt, 32));
      if (!__all(mt <= m_ + 8.f)) {   // rescale only when max actually grows (exp2 domain)
        const float mn = fmaxf(m_, mt);
        const float corr = exp2f(m_ - mn);
        m_ = mn;
        l_ *= corr;
#pragma unroll
        for (int r = 0; r < 16; ++r) { acc0[r] *= corr; acc1[r] *= corr; }
      }

      float rs = 0.f;
#pragma unroll
      for (int r = 0; r < 16; ++r) { st0[r] = exp2f(st0[r] - m_); rs += st0[r]; }
      if (do1) {
#pragma unroll
        for (int r = 0; r < 16; ++r) { st1[r] = exp2f(st1[r] - m_); rs += st1[r]; }
      }
      rs += __shfl_xor(rs, 32);
      l_ += rs;

      // ---- pack P to f16 words (consecutive-k pairs) ----
      unsigned W0[8], W1[8];
#pragma unroll
      for (int m = 0; m < 8; ++m) {
        H2 u; u.h = __builtin_amdgcn_cvt_pkrtz(st0[2 * m], st0[2 * m + 1]);
        W0[m] = u.u;
      }
      if (do1) {
#pragma unroll
        for (int m = 0; m < 8; ++m) {
          H2 u; u.h = __builtin_amdgcn_cvt_pkrtz(st1[2 * m], st1[2 * m + 1]);
          W1[m] = u.u;
        }
      }

      // ---- PV (O^T = V^T · P^T): B-frag of P via shfl_xor(32) redistribution ----
      __builtin_amdgcn_s_setprio(1);
#pragma unroll
      for (int c2 = 0; c2 < 2; ++c2) {
        const unsigned s0 = (unsigned)__shfl_xor((int)W0[4 * c2 + 0], 32);
        const unsigned s1 = (unsigned)__shfl_xor((int)W0[4 * c2 + 1], 32);
        const unsigned s2 = (unsigned)__shfl_xor((int)W0[4 * c2 + 2], 32);
        const unsigned s3 = (unsigned)__shfl_xor((int)W0[4 * c2 + 3], 32);
        H8 f;
        f.u[0] = hi ? s2 : W0[4 * c2 + 0];
        f.u[1] = hi ? s3 : W0[4 * c2 + 1];
        f.u[2] = hi ? W0[4 * c2 + 2] : s0;
        f.u[3] = hi ? W0[4 * c2 + 3] : s1;
        const int kx = c2 * 16 + hi * 8;
        const int d0 = ql, d1 = 32 + ql;
        const half8 va0 = *(const half8*)&VT[cur][d0 * 64 + (kx ^ swz(d0))];
        const half8 va1 = *(const half8*)&VT[cur][d1 * 64 + (kx ^ swz(d1))];
        acc0 = __builtin_amdgcn_mfma_f32_32x32x16_f16(va0, f.v, acc0, 0, 0, 0);
        acc1 = __builtin_amdgcn_mfma_f32_32x32x16_f16(va1, f.v, acc1, 0, 0, 0);
      }
      if (do1) {
#pragma unroll
        for (int c2 = 0; c2 < 2; ++c2) {
          const unsigned s0 = (unsigned)__shfl_xor((int)W1[4 * c2 + 0], 32);
          const unsigned s1 = (unsigned)__shfl_xor((int)W1[4 * c2 + 1], 32);
          const unsigned s2 = (unsigned)__shfl_xor((int)W1[4 * c2 + 2], 32);
          const unsigned s3 = (unsigned)__shfl_xor((int)W1[4 * c2 + 3], 32);
          H8 f;
          f.u[0] = hi ? s2 : W1[4 * c2 + 0];
          f.u[1] = hi ? s3 : W1[4 * c2 + 1];
          f.u[2] = hi ? W1[4 * c2 + 2] : s0;
          f.u[3] = hi ? W1[4 * c2 + 3] : s1;
          const int kx = (2 + c2) * 16 + hi * 8;
          const int d0 = ql, d1 = 32 + ql;
          const half8 va0 = *(const half8*)&VT[cur][d0 * 64 + (kx ^ swz(d0))];
          const half8 va1 = *(const half8*)&VT[cur][d1 * 64 + (kx ^ swz(d1))];
          acc0 = __builtin_amdgcn_mfma_f32_32x32x16_f16(va0, f.v, acc0, 0, 0, 0);
          acc1 = __builtin_amdgcn_mfma_f32_32x32x16_f16(va1, f.v, acc1, 0, 0, 0);
        }
      }
      __builtin_amdgcn_s_setprio(0);
    }

    // ---- write next tile to LDS (loads have had compute-time to land) ----
    if (doStage) {
#pragma unroll
      for (int i = 0; i < 2; ++i) stage_write(cur ^ 1, i, kst[i], vst[i]);
    }
  };

  // main loop: tiles in pairs, buffer index literal per phase
  for (int kt = 0; kt <= ktmax; kt += 2) {
    phase(kt, 0);
    phase(kt + 1, 1);
  }

  // ---- epilogue: normalize (lane-local l_) and store O^T frags as float4 ----
  const float inv = 1.0f / l_;
  float* obase = O + ((size_t)(b * CL + qg) * CH + h) * CE;
#pragma unroll
  for (int rq = 0; rq < 4; ++rq) {
    float4 o;
    o.x = acc0[4 * rq + 0] * inv; o.y = acc0[4 * rq + 1] * inv;
    o.z = acc0[4 * rq + 2] * inv; o.w = acc0[4 * rq + 3] * inv;
    *(float4*)(obase + rq * 8 + hi * 4) = o;
  }
#pragma unroll
  for (int rq = 0; rq < 4; ++rq) {
    float4 o;
    o.x = acc1[4 * rq + 0] * inv; o.y = acc1[4 * rq + 1] * inv;
    o.z = acc1[4 * rq + 2] * inv; o.w = acc1[4 * rq + 3] * inv;
    *(float4*)(obase + 32 + rq * 8 + hi * 4) = o;
  }
}

extern "C" void kernel_launch(void* const* d_in, const int* in_sizes, int n_in,
                              void* d_out, int out_size, void* d_ws, size_t ws_size,
                              hipStream_t stream) {
  const float* Q = (const float*)d_in[0];
  const float* K = (const float*)d_in[1];
  const float* V = (const float*)d_in[2];
  float* O = (float*)d_out;
  (void)d_ws; (void)ws_size; (void)in_sizes; (void)n_in; (void)out_size;
  // grid: 8 q-supertiles (balanced-paired) x 64 (b,h)
  attn512<<<dim3(8 * 64), dim3(512), 0, stream>>>(Q, K, V, O);
}

// Round 9
// 202.250 us; speedup vs baseline: 1.3228x; 1.3228x over previous
//
#include <hip/hip_runtime.h>

typedef _Float16 half8  __attribute__((ext_vector_type(8)));
typedef _Float16 half4v __attribute__((ext_vector_type(4)));
typedef __fp16   pk2    __attribute__((ext_vector_type(2)));  // cvt_pkrtz result type
typedef float    f32x16 __attribute__((ext_vector_type(16)));

constexpr int CL = 2048, CH = 16, CE = 64;
constexpr int RS = CH * CE;  // 1024 floats between consecutive seq positions
constexpr size_t PANEL_HALFS = (size_t)4 * 16 * 2048 * 64;  // one full K (or V) in fp16
constexpr size_t WS_NEED = PANEL_HALFS * 2 * sizeof(_Float16) * 2;  // K + V panels

union H8 { half8 v; pk2 h[4]; unsigned u[4]; };
union H4 { half4v v; pk2 h[2]; };
union H2 { pk2 h; unsigned u; };

// XOR swizzle on the inner (k/e) index, in units of 8 halves (16B).
__device__ __forceinline__ int swz(int r) { return ((r ^ (r >> 3)) & 7) << 3; }

// global->LDS direct DMA, 16B per lane. LDS dest is wave-uniform base + lane*16;
// global src is per-lane. (CK-style addrspace casts.)
typedef const __attribute__((address_space(1))) unsigned* gas_t;
typedef __attribute__((address_space(3))) unsigned* las_t;
__device__ __forceinline__ void gload_lds16(const _Float16* g, _Float16* l) {
  __builtin_amdgcn_global_load_lds((gas_t)g, (las_t)(unsigned long)(l), 16, 0, 0);
}

// ---------------- pre-pass: K,V fp32 -> fp16 panels in LDS-tile layout ----------------
// Panel layout per (bh, tile): 4096 halfs. K: elem (row,e) at row*64 + (e^swz(row)).
// V^T: elem (k,d) at d*64 + (k^swz(d)).
__global__ __launch_bounds__(256, 4)
void convert_kv(const float* __restrict__ K, const float* __restrict__ V,
                _Float16* __restrict__ Kh, _Float16* __restrict__ Vh) {
  __shared__ _Float16 T[64 * 68];  // V tile staged [k][d] padded for transpose
  const int x = blockIdx.x;
  const int t = x & 31, bh = x >> 5;
  const int b = bh >> 4, h = bh & 15;
  const int tid = threadIdx.x;
  const float* Kb = K + ((size_t)b * CL * CH + h) * CE + (size_t)(t * 64) * RS;
  const float* Vb = V + ((size_t)b * CL * CH + h) * CE + (size_t)(t * 64) * RS;
  _Float16* Kt = Kh + (size_t)(bh * 32 + t) * 4096;
  _Float16* Vt = Vh + (size_t)(bh * 32 + t) * 4096;

#pragma unroll
  for (int f = 0; f < 2; ++f) {
    const int oidx = f * 256 + tid;
    const int row = oidx >> 3, o = oidx & 7;  // 8 threads cover one 64-float row
    // K octet -> panel (swizzled, 16B store)
    const float4 k0 = *(const float4*)(Kb + (size_t)row * RS + o * 8);
    const float4 k1 = *(const float4*)(Kb + (size_t)row * RS + o * 8 + 4);
    H8 uk;
    uk.h[0] = __builtin_amdgcn_cvt_pkrtz(k0.x, k0.y);
    uk.h[1] = __builtin_amdgcn_cvt_pkrtz(k0.z, k0.w);
    uk.h[2] = __builtin_amdgcn_cvt_pkrtz(k1.x, k1.y);
    uk.h[3] = __builtin_amdgcn_cvt_pkrtz(k1.z, k1.w);
    *(half8*)&Kt[row * 64 + ((o * 8) ^ swz(row))] = uk.v;
    // V octet -> LDS (row-major, padded)
    const float4 v0 = *(const float4*)(Vb + (size_t)row * RS + o * 8);
    const float4 v1 = *(const float4*)(Vb + (size_t)row * RS + o * 8 + 4);
    H4 a, c;
    a.h[0] = __builtin_amdgcn_cvt_pkrtz(v0.x, v0.y);
    a.h[1] = __builtin_amdgcn_cvt_pkrtz(v0.z, v0.w);
    c.h[0] = __builtin_amdgcn_cvt_pkrtz(v1.x, v1.y);
    c.h[1] = __builtin_amdgcn_cvt_pkrtz(v1.z, v1.w);
    *(half4v*)&T[row * 68 + o * 8] = a.v;       // 8B aligned (68*2B=136B rows)
    *(half4v*)&T[row * 68 + o * 8 + 4] = c.v;
  }
  __syncthreads();
#pragma unroll
  for (int f = 0; f < 2; ++f) {
    const int oidx = f * 256 + tid;
    const int d = oidx >> 3, ko = oidx & 7;
    half8 r;
#pragma unroll
    for (int j = 0; j < 8; ++j) r[j] = T[(ko * 8 + j) * 68 + d];
    *(half8*)&Vt[d * 64 + ((ko * 8) ^ swz(d))] = r;
  }
}

// ---------------- main kernel: DMA staging from pre-converted panels ----------------
__global__ __launch_bounds__(256, 3)
void attn_dma(const float* __restrict__ Q, const _Float16* __restrict__ Kh,
              const _Float16* __restrict__ Vh, float* __restrict__ O) {
  __shared__ __align__(16) _Float16 KS[2][64 * 64];
  __shared__ __align__(16) _Float16 VT[2][64 * 64];

  const int tid = threadIdx.x;
  const int w  = tid >> 6, l = tid & 63;
  const int hi = l >> 5,  ql = l & 31;

  const int bid = blockIdx.x;
  const int bh  = bid & 63;          // heads fastest
  const int qt  = 15 - (bid >> 6);   // heavy blocks first
  const int b = bh >> 4, h = bh & 15;
  const int qg0 = qt * 128 + w * 32;
  const int qg  = qg0 + ql;

  // ---- Q^T B-frags (swapped QK^T) ----
  const float* qptr = Q + ((size_t)(b * CL + qg) * CH + h) * CE;
  const float qs = 0.125f * 1.44269504089f;  // scale * log2(e)
  half8 qf[4];
#pragma unroll
  for (int c = 0; c < 4; ++c) {
    const float4 x0 = *(const float4*)(qptr + c * 16 + hi * 8);
    const float4 x1 = *(const float4*)(qptr + c * 16 + hi * 8 + 4);
    H8 t;
    t.h[0] = __builtin_amdgcn_cvt_pkrtz(x0.x * qs, x0.y * qs);
    t.h[1] = __builtin_amdgcn_cvt_pkrtz(x0.z * qs, x0.w * qs);
    t.h[2] = __builtin_amdgcn_cvt_pkrtz(x1.x * qs, x1.y * qs);
    t.h[3] = __builtin_amdgcn_cvt_pkrtz(x1.z * qs, x1.w * qs);
    qf[c] = t.v;
  }

  f32x16 acc0, acc1;
#pragma unroll
  for (int i = 0; i < 16; ++i) { acc0[i] = 0.f; acc1[i] = 0.f; }
  float m_ = -1e30f, l_ = 0.f;

  const size_t pbase = (size_t)bh * 32;
  const int ktmax  = 2 * qt + 1;
  const int ktlast = 2 * qt + (w >> 1);

  // DMA one 64-key tile (K 8KB + V^T 8KB) into buffer buf; each wave moves 2KB+2KB.
  auto stage_dma = [&](int buf, int tg) {
    const _Float16* Kt = Kh + (pbase + tg) * 4096;
    const _Float16* Vt = Vh + (pbase + tg) * 4096;
#pragma unroll
    for (int i = 0; i < 2; ++i) {
      gload_lds16(Kt + w * 1024 + i * 512 + l * 8, &KS[buf][w * 1024 + i * 512]);
      gload_lds16(Vt + w * 1024 + i * 512 + l * 8, &VT[buf][w * 1024 + i * 512]);
    }
  };

  stage_dma(0, 0);  // prologue; first barrier drains vmcnt

  for (int kt = 0; kt <= ktmax; ++kt) {
    const int cur = kt & 1;
    __syncthreads();  // drains DMA (tile kt landed); prior reads of buf cur^1 done

    if (kt < ktmax) stage_dma(cur ^ 1, kt + 1);  // fire-and-forget for next phase

    if (kt <= ktlast) {
      const int kb = kt * 64;
      const bool do1 = (qg0 + 31) >= (kb + 32);

      // ---- swapped QK^T: S^T[k][q] = K_tile · Q^T ----
      f32x16 st0, st1;
#pragma unroll
      for (int i = 0; i < 16; ++i) { st0[i] = 0.f; st1[i] = 0.f; }
#pragma unroll
      for (int c = 0; c < 4; ++c) {
        const half8 ka = *(const half8*)&KS[cur][ql * 64 + ((c * 16 + hi * 8) ^ swz(ql))];
        st0 = __builtin_amdgcn_mfma_f32_32x32x16_f16(ka, qf[c], st0, 0, 0, 0);
      }
      if (do1) {
#pragma unroll
        for (int c = 0; c < 4; ++c) {
          const int row = 32 + ql;
          const half8 ka = *(const half8*)&KS[cur][row * 64 + ((c * 16 + hi * 8) ^ swz(row))];
          st1 = __builtin_amdgcn_mfma_f32_32x32x16_f16(ka, qf[c], st1, 0, 0, 0);
        }
      }

      // ---- causal mask (diagonal tile); reg r -> k row (r&3)+8*(r>>2)+4*hi ----
      if (kt == ktlast) {
#pragma unroll
        for (int r = 0; r < 16; ++r) {
          const int ko = (r & 3) + 8 * (r >> 2) + 4 * hi;
          if (kb + ko > qg) st0[r] = -1e30f;
          if (kb + 32 + ko > qg) st1[r] = -1e30f;
        }
      }

      // ---- in-lane online softmax ----
      float mt;
      {
        float a = fmaxf(fmaxf(fmaxf(st0[0], st0[1]), fmaxf(st0[2], st0[3])),
                        fmaxf(fmaxf(st0[4], st0[5]), fmaxf(st0[6], st0[7])));
        float bm = fmaxf(fmaxf(fmaxf(st0[8], st0[9]), fmaxf(st0[10], st0[11])),
                         fmaxf(fmaxf(st0[12], st0[13]), fmaxf(st0[14], st0[15])));
        mt = fmaxf(a, bm);
        if (do1) {
          float c2 = fmaxf(fmaxf(fmaxf(st1[0], st1[1]), fmaxf(st1[2], st1[3])),
                           fmaxf(fmaxf(st1[4], st1[5]), fmaxf(st1[6], st1[7])));
          float d2 = fmaxf(fmaxf(fmaxf(st1[8], st1[9]), fmaxf(st1[10], st1[11])),
                           fmaxf(fmaxf(st1[12], st1[13]), fmaxf(st1[14], st1[15])));
          mt = fmaxf(mt, fmaxf(c2, d2));
        }
      }
      mt = fmaxf(mt, __shfl_xor(mt, 32));
      const float mn = fmaxf(m_, mt);
      const float corr = exp2f(m_ - mn);
      m_ = mn;

      float rs = 0.f;
#pragma unroll
      for (int r = 0; r < 16; ++r) { st0[r] = exp2f(st0[r] - mn); rs += st0[r]; }
      if (do1) {
#pragma unroll
        for (int r = 0; r < 16; ++r) { st1[r] = exp2f(st1[r] - mn); rs += st1[r]; }
      }
      rs += __shfl_xor(rs, 32);
      l_ = l_ * corr + rs;
#pragma unroll
      for (int r = 0; r < 16; ++r) { acc0[r] *= corr; acc1[r] *= corr; }

      // ---- pack P to f16 words ----
      unsigned W0[8], W1[8];
#pragma unroll
      for (int m = 0; m < 8; ++m) {
        H2 u; u.h = __builtin_amdgcn_cvt_pkrtz(st0[2 * m], st0[2 * m + 1]);
        W0[m] = u.u;
      }
      if (do1) {
#pragma unroll
        for (int m = 0; m < 8; ++m) {
          H2 u; u.h = __builtin_amdgcn_cvt_pkrtz(st1[2 * m], st1[2 * m + 1]);
          W1[m] = u.u;
        }
      }

      // ---- PV (O^T = V^T · P^T): P B-frags via shfl_xor(32) ----
#pragma unroll
      for (int c2 = 0; c2 < 2; ++c2) {
        const unsigned s0 = (unsigned)__shfl_xor((int)W0[4 * c2 + 0], 32);
        const unsigned s1 = (unsigned)__shfl_xor((int)W0[4 * c2 + 1], 32);
        const unsigned s2 = (unsigned)__shfl_xor((int)W0[4 * c2 + 2], 32);
        const unsigned s3 = (unsigned)__shfl_xor((int)W0[4 * c2 + 3], 32);
        H8 f;
        f.u[0] = hi ? s2 : W0[4 * c2 + 0];
        f.u[1] = hi ? s3 : W0[4 * c2 + 1];
        f.u[2] = hi ? W0[4 * c2 + 2] : s0;
        f.u[3] = hi ? W0[4 * c2 + 3] : s1;
        const int kx = c2 * 16 + hi * 8;
        const int d0 = ql, d1 = 32 + ql;
        const half8 va0 = *(const half8*)&VT[cur][d0 * 64 + (kx ^ swz(d0))];
        const half8 va1 = *(const half8*)&VT[cur][d1 * 64 + (kx ^ swz(d1))];
        acc0 = __builtin_amdgcn_mfma_f32_32x32x16_f16(va0, f.v, acc0, 0, 0, 0);
        acc1 = __builtin_amdgcn_mfma_f32_32x32x16_f16(va1, f.v, acc1, 0, 0, 0);
      }
      if (do1) {
#pragma unroll
        for (int c2 = 0; c2 < 2; ++c2) {
          const unsigned s0 = (unsigned)__shfl_xor((int)W1[4 * c2 + 0], 32);
          const unsigned s1 = (unsigned)__shfl_xor((int)W1[4 * c2 + 1], 32);
          const unsigned s2 = (unsigned)__shfl_xor((int)W1[4 * c2 + 2], 32);
          const unsigned s3 = (unsigned)__shfl_xor((int)W1[4 * c2 + 3], 32);
          H8 f;
          f.u[0] = hi ? s2 : W1[4 * c2 + 0];
          f.u[1] = hi ? s3 : W1[4 * c2 + 1];
          f.u[2] = hi ? W1[4 * c2 + 2] : s0;
          f.u[3] = hi ? W1[4 * c2 + 3] : s1;
          const int kx = (2 + c2) * 16 + hi * 8;
          const int d0 = ql, d1 = 32 + ql;
          const half8 va0 = *(const half8*)&VT[cur][d0 * 64 + (kx ^ swz(d0))];
          const half8 va1 = *(const half8*)&VT[cur][d1 * 64 + (kx ^ swz(d1))];
          acc0 = __builtin_amdgcn_mfma_f32_32x32x16_f16(va0, f.v, acc0, 0, 0, 0);
          acc1 = __builtin_amdgcn_mfma_f32_32x32x16_f16(va1, f.v, acc1, 0, 0, 0);
        }
      }
    }
  }

  // ---- epilogue (same as round 5) ----
  const float inv = 1.0f / l_;
  float* obase = O + ((size_t)(b * CL + qg) * CH + h) * CE;
#pragma unroll
  for (int rq = 0; rq < 4; ++rq) {
    float4 o;
    o.x = acc0[4 * rq + 0] * inv; o.y = acc0[4 * rq + 1] * inv;
    o.z = acc0[4 * rq + 2] * inv; o.w = acc0[4 * rq + 3] * inv;
    *(float4*)(obase + rq * 8 + hi * 4) = o;
  }
#pragma unroll
  for (int rq = 0; rq < 4; ++rq) {
    float4 o;
    o.x = acc1[4 * rq + 0] * inv; o.y = acc1[4 * rq + 1] * inv;
    o.z = acc1[4 * rq + 2] * inv; o.w = acc1[4 * rq + 3] * inv;
    *(float4*)(obase + 32 + rq * 8 + hi * 4) = o;
  }
}

// ---------------- fallback: round-5 kernel verbatim (used if ws too small) ----------------
__global__ __launch_bounds__(256, 3)
void attn32(const float* __restrict__ Q, const float* __restrict__ K,
            const float* __restrict__ V, float* __restrict__ O) {
  __shared__ _Float16 KS[2][64 * 64];
  __shared__ _Float16 VT[2][64 * 64];

  const int tid = threadIdx.x;
  const int w  = tid >> 6, l = tid & 63;
  const int hi = l >> 5,  ql = l & 31;

  const int bid = blockIdx.x;
  const int bh  = bid & 63;
  const int qt  = 15 - (bid >> 6);
  const int b = bh >> 4, h = bh & 15;
  const int qg0 = qt * 128 + w * 32;
  const int qg  = qg0 + ql;

  const float* qptr = Q + ((size_t)(b * CL + qg) * CH + h) * CE;
  const float qs = 0.125f * 1.44269504089f;
  half8 qf[4];
#pragma unroll
  for (int c = 0; c < 4; ++c) {
    const float4 x0 = *(const float4*)(qptr + c * 16 + hi * 8);
    const float4 x1 = *(const float4*)(qptr + c * 16 + hi * 8 + 4);
    H8 t;
    t.h[0] = __builtin_amdgcn_cvt_pkrtz(x0.x * qs, x0.y * qs);
    t.h[1] = __builtin_amdgcn_cvt_pkrtz(x0.z * qs, x0.w * qs);
    t.h[2] = __builtin_amdgcn_cvt_pkrtz(x1.x * qs, x1.y * qs);
    t.h[3] = __builtin_amdgcn_cvt_pkrtz(x1.z * qs, x1.w * qs);
    qf[c] = t.v;
  }

  f32x16 acc0, acc1;
#pragma unroll
  for (int i = 0; i < 16; ++i) { acc0[i] = 0.f; acc1[i] = 0.f; }
  float m_ = -1e30f, l_ = 0.f;

  const float* Kb = K + ((size_t)b * CL * CH + h) * CE;
  const float* Vb = V + ((size_t)b * CL * CH + h) * CE;
  const int r0 = tid >> 4, c4 = tid & 15;
  const int ktmax  = 2 * qt + 1;
  const int ktlast = 2 * qt + (w >> 1);

  auto stage_write = [&](int buf, int i, const float4& kx, const float4& vx) {
    const int row = i * 16 + r0;
    H4 t;
    t.h[0] = __builtin_amdgcn_cvt_pkrtz(kx.x, kx.y);
    t.h[1] = __builtin_amdgcn_cvt_pkrtz(kx.z, kx.w);
    *(half4v*)&KS[buf][row * 64 + ((c4 * 4) ^ swz(row))] = t.v;
    VT[buf][(c4 * 4 + 0) * 64 + (row ^ swz(c4 * 4 + 0))] = (_Float16)vx.x;
    VT[buf][(c4 * 4 + 1) * 64 + (row ^ swz(c4 * 4 + 1))] = (_Float16)vx.y;
    VT[buf][(c4 * 4 + 2) * 64 + (row ^ swz(c4 * 4 + 2))] = (_Float16)vx.z;
    VT[buf][(c4 * 4 + 3) * 64 + (row ^ swz(c4 * 4 + 3))] = (_Float16)vx.w;
  };

#pragma unroll
  for (int i = 0; i < 4; ++i) {
    const int row = i * 16 + r0;
    const float4 kx = *(const float4*)(Kb + (size_t)row * RS + c4 * 4);
    const float4 vx = *(const float4*)(Vb + (size_t)row * RS + c4 * 4);
    stage_write(0, i, kx, vx);
  }

  for (int kt = 0; kt <= ktmax; ++kt) {
    const int cur = kt & 1, nxt = cur ^ 1;
    __syncthreads();

    float4 kst[4], vst[4];
    const bool doStage = (kt < ktmax);
    if (doStage) {
      const int kb1 = (kt + 1) * 64;
#pragma unroll
      for (int i = 0; i < 4; ++i) {
        const int row = kb1 + i * 16 + r0;
        kst[i] = *(const float4*)(Kb + (size_t)row * RS + c4 * 4);
        vst[i] = *(const float4*)(Vb + (size_t)row * RS + c4 * 4);
      }
    }

    if (kt <= ktlast) {
      const int kb = kt * 64;
      const bool do1 = (qg0 + 31) >= (kb + 32);

      f32x16 st0, st1;
#pragma unroll
      for (int i = 0; i < 16; ++i) { st0[i] = 0.f; st1[i] = 0.f; }
#pragma unroll
      for (int c = 0; c < 4; ++c) {
        const half8 ka = *(const half8*)&KS[cur][ql * 64 + ((c * 16 + hi * 8) ^ swz(ql))];
        st0 = __builtin_amdgcn_mfma_f32_32x32x16_f16(ka, qf[c], st0, 0, 0, 0);
      }
      if (do1) {
#pragma unroll
        for (int c = 0; c < 4; ++c) {
          const int row = 32 + ql;
          const half8 ka = *(const half8*)&KS[cur][row * 64 + ((c * 16 + hi * 8) ^ swz(row))];
          st1 = __builtin_amdgcn_mfma_f32_32x32x16_f16(ka, qf[c], st1, 0, 0, 0);
        }
      }

      if (kt == ktlast) {
#pragma unroll
        for (int r = 0; r < 16; ++r) {
          const int ko = (r & 3) + 8 * (r >> 2) + 4 * hi;
          if (kb + ko > qg) st0[r] = -1e30f;
          if (kb + 32 + ko > qg) st1[r] = -1e30f;
        }
      }

      float mt;
      {
        float a = fmaxf(fmaxf(fmaxf(st0[0], st0[1]), fmaxf(st0[2], st0[3])),
                        fmaxf(fmaxf(st0[4], st0[5]), fmaxf(st0[6], st0[7])));
        float bm = fmaxf(fmaxf(fmaxf(st0[8], st0[9]), fmaxf(st0[10], st0[11])),
                         fmaxf(fmaxf(st0[12], st0[13]), fmaxf(st0[14], st0[15])));
        mt = fmaxf(a, bm);
        if (do1) {
          float c2 = fmaxf(fmaxf(fmaxf(st1[0], st1[1]), fmaxf(st1[2], st1[3])),
                           fmaxf(fmaxf(st1[4], st1[5]), fmaxf(st1[6], st1[7])));
          float d2 = fmaxf(fmaxf(fmaxf(st1[8], st1[9]), fmaxf(st1[10], st1[11])),
                           fmaxf(fmaxf(st1[12], st1[13]), fmaxf(st1[14], st1[15])));
          mt = fmaxf(mt, fmaxf(c2, d2));
        }
      }
      mt = fmaxf(mt, __shfl_xor(mt, 32));
      const float mn = fmaxf(m_, mt);
      const float corr = exp2f(m_ - mn);
      m_ = mn;

      float rs = 0.f;
#pragma unroll
      for (int r = 0; r < 16; ++r) { st0[r] = exp2f(st0[r] - mn); rs += st0[r]; }
      if (do1) {
#pragma unroll
        for (int r = 0; r < 16; ++r) { st1[r] = exp2f(st1[r] - mn); rs += st1[r]; }
      }
      rs += __shfl_xor(rs, 32);
      l_ = l_ * corr + rs;
#pragma unroll
      for (int r = 0; r < 16; ++r) { acc0[r] *= corr; acc1[r] *= corr; }

      unsigned W0[8], W1[8];
#pragma unroll
      for (int m = 0; m < 8; ++m) {
        H2 u; u.h = __builtin_amdgcn_cvt_pkrtz(st0[2 * m], st0[2 * m + 1]);
        W0[m] = u.u;
      }
      if (do1) {
#pragma unroll
        for (int m = 0; m < 8; ++m) {
          H2 u; u.h = __builtin_amdgcn_cvt_pkrtz(st1[2 * m], st1[2 * m + 1]);
          W1[m] = u.u;
        }
      }

#pragma unroll
      for (int c2 = 0; c2 < 2; ++c2) {
        const unsigned s0 = (unsigned)__shfl_xor((int)W0[4 * c2 + 0], 32);
        const unsigned s1 = (unsigned)__shfl_xor((int)W0[4 * c2 + 1], 32);
        const unsigned s2 = (unsigned)__shfl_xor((int)W0[4 * c2 + 2], 32);
        const unsigned s3 = (unsigned)__shfl_xor((int)W0[4 * c2 + 3], 32);
        H8 f;
        f.u[0] = hi ? s2 : W0[4 * c2 + 0];
        f.u[1] = hi ? s3 : W0[4 * c2 + 1];
        f.u[2] = hi ? W0[4 * c2 + 2] : s0;
        f.u[3] = hi ? W0[4 * c2 + 3] : s1;
        const int kx = c2 * 16 + hi * 8;
        const int d0 = ql, d1 = 32 + ql;
        const half8 va0 = *(const half8*)&VT[cur][d0 * 64 + (kx ^ swz(d0))];
        const half8 va1 = *(const half8*)&VT[cur][d1 * 64 + (kx ^ swz(d1))];
        acc0 = __builtin_amdgcn_mfma_f32_32x32x16_f16(va0, f.v, acc0, 0, 0, 0);
        acc1 = __builtin_amdgcn_mfma_f32_32x32x16_f16(va1, f.v, acc1, 0, 0, 0);
      }
      if (do1) {
#pragma unroll
        for (int c2 = 0; c2 < 2; ++c2) {
          const unsigned s0 = (unsigned)__shfl_xor((int)W1[4 * c2 + 0], 32);
          const unsigned s1 = (unsigned)__shfl_xor((int)W1[4 * c2 + 1], 32);
          const unsigned s2 = (unsigned)__shfl_xor((int)W1[4 * c2 + 2], 32);
          const unsigned s3 = (unsigned)__shfl_xor((int)W1[4 * c2 + 3], 32);
          H8 f;
          f.u[0] = hi ? s2 : W1[4 * c2 + 0];
          f.u[1] = hi ? s3 : W1[4 * c2 + 1];
          f.u[2] = hi ? W1[4 * c2 + 2] : s0;
          f.u[3] = hi ? W1[4 * c2 + 3] : s1;
          const int kx = (2 + c2) * 16 + hi * 8;
          const int d0 = ql, d1 = 32 + ql;
          const half8 va0 = *(const half8*)&VT[cur][d0 * 64 + (kx ^ swz(d0))];
          const half8 va1 = *(const half8*)&VT[cur][d1 * 64 + (kx ^ swz(d1))];
          acc0 = __builtin_amdgcn_mfma_f32_32x32x16_f16(va0, f.v, acc0, 0, 0, 0);
          acc1 = __builtin_amdgcn_mfma_f32_32x32x16_f16(va1, f.v, acc1, 0, 0, 0);
        }
      }
    }

    if (doStage) {
#pragma unroll
      for (int i = 0; i < 4; ++i) stage_write(nxt, i, kst[i], vst[i]);
    }
  }

  const float inv = 1.0f / l_;
  float* obase = O + ((size_t)(b * CL + qg) * CH + h) * CE;
#pragma unroll
  for (int rq = 0; rq < 4; ++rq) {
    float4 o;
    o.x = acc0[4 * rq + 0] * inv; o.y = acc0[4 * rq + 1] * inv;
    o.z = acc0[4 * rq + 2] * inv; o.w = acc0[4 * rq + 3] * inv;
    *(float4*)(obase + rq * 8 + hi * 4) = o;
  }
#pragma unroll
  for (int rq = 0; rq < 4; ++rq) {
    float4 o;
    o.x = acc1[4 * rq + 0] * inv; o.y = acc1[4 * rq + 1] * inv;
    o.z = acc1[4 * rq + 2] * inv; o.w = acc1[4 * rq + 3] * inv;
    *(float4*)(obase + 32 + rq * 8 + hi * 4) = o;
  }
}

extern "C" void kernel_launch(void* const* d_in, const int* in_sizes, int n_in,
                              void* d_out, int out_size, void* d_ws, size_t ws_size,
                              hipStream_t stream) {
  const float* Q = (const float*)d_in[0];
  const float* K = (const float*)d_in[1];
  const float* V = (const float*)d_in[2];
  float* O = (float*)d_out;
  (void)in_sizes; (void)n_in; (void)out_size;
  if (ws_size >= WS_NEED) {
    _Float16* Kh = (_Float16*)d_ws;
    _Float16* Vh = Kh + PANEL_HALFS;
    convert_kv<<<dim3(64 * 32), dim3(256), 0, stream>>>(K, V, Kh, Vh);
    attn_dma<<<dim3(16 * 64), dim3(256), 0, stream>>>(Q, Kh, Vh, O);
  } else {
    attn32<<<dim3(16 * 64), dim3(256), 0, stream>>>(Q, K, V, O);
  }
}